// Round 1
// baseline (301.065 us; speedup 1.0000x reference)
//
#include <hip/hip_runtime.h>
#include <math.h>

#define FFT_N 16384
#define LOG2N 14
#define NT 512
#define NBFLY (FFT_N / 4)              // 4096 radix-4 butterflies per stage
#define LDSZ (FFT_N + (FFT_N >> 5))    // 16896 float2 = 132 KiB (padded)
#define IDX(i) ((i) + ((i) >> 5))      // pad 1 float2 per 32 to spread banks

#define B_DIM 8
#define H_DIM 256

__device__ __forceinline__ float2 cmul(float2 a, float2 b) {
    return make_float2(a.x * b.x - a.y * b.y, a.x * b.y + a.y * b.x);
}
__device__ __forceinline__ float2 cadd(float2 a, float2 b) { return make_float2(a.x + b.x, a.y + b.y); }
__device__ __forceinline__ float2 csub(float2 a, float2 b) { return make_float2(a.x - b.x, a.y - b.y); }
__device__ __forceinline__ float2 mulnegi(float2 z) { return make_float2(z.y, -z.x); }  // -i*z
__device__ __forceinline__ float2 mulposi(float2 z) { return make_float2(-z.y, z.x); }  // +i*z

// Forward radix-4 DIF: natural input -> bit-reversed output. 7 stages (16384 = 4^7).
// tw[t] = exp(-2*pi*i*t/N), full table t in [0,N).
__device__ __forceinline__ void fft_fwd(float2* s, const float2* __restrict__ tw, int tid) {
#pragma unroll
    for (int stage = 0; stage < 7; ++stage) {
        const int q  = FFT_N >> (2 * stage + 2);  // len/4
        const int st = 1 << (2 * stage);          // N/len (twiddle stride)
#pragma unroll
        for (int it = 0; it < NBFLY / NT; ++it) {
            int j = tid + it * NT;
            int t = j & (q - 1);
            int base = (j << 2) - 3 * t;          // blk*len + t
            float2 a = s[IDX(base)];
            float2 b = s[IDX(base + q)];
            float2 c = s[IDX(base + 2 * q)];
            float2 d = s[IDX(base + 3 * q)];
            float2 apc = cadd(a, c), amc = csub(a, c);
            float2 bpd = cadd(b, d), bmd = csub(b, d);
            float2 w1 = tw[t * st];
            float2 w2 = cmul(w1, w1);
            float2 w3 = cmul(w2, w1);
            float2 nib = mulnegi(bmd);            // -i*(b-d)
            s[IDX(base)]         = cadd(apc, bpd);
            s[IDX(base + q)]     = cmul(csub(apc, bpd), w2);
            s[IDX(base + 2 * q)] = cmul(cadd(amc, nib), w1);
            s[IDX(base + 3 * q)] = cmul(csub(amc, nib), w3);
        }
        __syncthreads();
    }
}

// Inverse radix-4 DIT: bit-reversed input -> natural output (unscaled; 1/N folded by caller).
__device__ __forceinline__ void fft_inv(float2* s, const float2* __restrict__ tw, int tid) {
#pragma unroll
    for (int stage = 6; stage >= 0; --stage) {
        const int q  = FFT_N >> (2 * stage + 2);
        const int st = 1 << (2 * stage);
#pragma unroll
        for (int it = 0; it < NBFLY / NT; ++it) {
            int j = tid + it * NT;
            int t = j & (q - 1);
            int base = (j << 2) - 3 * t;
            float2 a = s[IDX(base)];
            float2 b = s[IDX(base + q)];
            float2 c = s[IDX(base + 2 * q)];
            float2 d = s[IDX(base + 3 * q)];
            float2 w1 = tw[t * st]; w1.y = -w1.y; // conj -> e^{+2pi i t/len}
            float2 w2 = cmul(w1, w1);
            float2 bt = cmul(b, w2), dt = cmul(d, w2);
            float2 A  = cadd(a, bt), Bb = csub(a, bt);
            float2 C  = cadd(c, dt), Dd = csub(c, dt);
            float2 Cw = cmul(C, w1);
            float2 Dw = mulposi(cmul(Dd, w1));
            s[IDX(base)]         = cadd(A, Cw);
            s[IDX(base + 2 * q)] = csub(A, Cw);
            s[IDX(base + q)]     = cadd(Bb, Dw);
            s[IDX(base + 3 * q)] = csub(Bb, Dw);
        }
        __syncthreads();
    }
}

__global__ void twiddle_init(float2* __restrict__ tw) {
    int t = blockIdx.x * blockDim.x + threadIdx.x;
    if (t < FFT_N) {
        float ang = -2.0f * 3.14159265358979323846f * (float)t / (float)FFT_N;
        float sv, cv;
        sincosf(ang, &sv, &cv);
        tw[t] = make_float2(cv, sv);
    }
}

// Forward FFT of each kernel row k[h] -> Kf[h] (bit-reversed order, matching fft_fwd).
__global__ __launch_bounds__(NT) void kfft_kernel(const float* __restrict__ k,
                                                  const float2* __restrict__ tw,
                                                  float2* __restrict__ Kf) {
    __shared__ float2 s[LDSZ];
    const int h = blockIdx.x;
    const int tid = threadIdx.x;
    const float* krow = k + (size_t)h * FFT_N;
#pragma unroll
    for (int it = 0; it < FFT_N / (NT * 4); ++it) {
        int e = (tid + it * NT) * 4;
        float4 v = *(const float4*)(krow + e);
        s[IDX(e)]     = make_float2(v.x, 0.f);
        s[IDX(e + 1)] = make_float2(v.y, 0.f);
        s[IDX(e + 2)] = make_float2(v.z, 0.f);
        s[IDX(e + 3)] = make_float2(v.w, 0.f);
    }
    __syncthreads();
    fft_fwd(s, tw, tid);
    float2* out = Kf + (size_t)h * FFT_N;
#pragma unroll
    for (int it = 0; it < FFT_N / NT; ++it) {
        int e = tid + it * NT;
        out[e] = s[IDX(e)];
    }
}

// Each workgroup: rows (2p, h) and (2p+1, h) packed as z = u0 + i*u1.
// ifft(fft(z)*Kf) -> real part = conv(u0,k_h), imag = conv(u1,k_h).
__global__ __launch_bounds__(NT) void conv_kernel(const float* __restrict__ u,
                                                  const float* __restrict__ D,
                                                  const float2* __restrict__ tw,
                                                  const float2* __restrict__ Kf,
                                                  float* __restrict__ out) {
    __shared__ float2 s[LDSZ];
    const int h = blockIdx.x & (H_DIM - 1);
    const int p = blockIdx.x >> 8;  // pair index 0..3
    const int tid = threadIdx.x;
    const size_t row0 = ((size_t)(2 * p) * H_DIM + h) * FFT_N;
    const size_t row1 = row0 + (size_t)H_DIM * FFT_N;
    const float* u0 = u + row0;
    const float* u1 = u + row1;

#pragma unroll
    for (int it = 0; it < FFT_N / (NT * 4); ++it) {
        int e = (tid + it * NT) * 4;
        float4 x = *(const float4*)(u0 + e);
        float4 y = *(const float4*)(u1 + e);
        s[IDX(e)]     = make_float2(x.x, y.x);
        s[IDX(e + 1)] = make_float2(x.y, y.y);
        s[IDX(e + 2)] = make_float2(x.z, y.z);
        s[IDX(e + 3)] = make_float2(x.w, y.w);
    }
    __syncthreads();

    fft_fwd(s, tw, tid);

    const float2* kf = Kf + (size_t)h * FFT_N;
    const float invN = 1.0f / (float)FFT_N;
#pragma unroll
    for (int it = 0; it < FFT_N / NT; ++it) {
        int e = tid + it * NT;
        float2 z = s[IDX(e)];
        float2 r = cmul(z, kf[e]);
        s[IDX(e)] = make_float2(r.x * invN, r.y * invN);
    }
    __syncthreads();

    fft_inv(s, tw, tid);
    // fft_inv ends with __syncthreads()

    const float dh = D[h * (H_DIM + 1)];  // diag(D)[h]
    float* o0 = out + row0;
    float* o1 = out + row1;
#pragma unroll
    for (int it = 0; it < FFT_N / (NT * 4); ++it) {
        int e = (tid + it * NT) * 4;
        float4 x = *(const float4*)(u0 + e);
        float4 y = *(const float4*)(u1 + e);
        float2 s0 = s[IDX(e)], s1 = s[IDX(e + 1)], s2 = s[IDX(e + 2)], s3 = s[IDX(e + 3)];
        float4 r0, r1;
        r0.x = tanhf(s0.x + dh * x.x);  r1.x = tanhf(s0.y + dh * y.x);
        r0.y = tanhf(s1.x + dh * x.y);  r1.y = tanhf(s1.y + dh * y.y);
        r0.z = tanhf(s2.x + dh * x.z);  r1.z = tanhf(s2.y + dh * y.z);
        r0.w = tanhf(s3.x + dh * x.w);  r1.w = tanhf(s3.y + dh * y.w);
        *(float4*)(o0 + e) = r0;
        *(float4*)(o1 + e) = r1;
    }
}

extern "C" void kernel_launch(void* const* d_in, const int* in_sizes, int n_in,
                              void* d_out, int out_size, void* d_ws, size_t ws_size,
                              hipStream_t stream) {
    const float* u = (const float*)d_in[0];   // (B,H,L) f32
    const float* k = (const float*)d_in[1];   // (H,L)   f32
    const float* D = (const float*)d_in[2];   // (H,H)   f32
    float* out = (float*)d_out;

    // ws layout: [0, 128KiB) twiddle table (16384 float2); then Kf (256*16384 float2 = 32 MiB)
    float2* tw = (float2*)d_ws;
    float2* Kf = tw + FFT_N;

    twiddle_init<<<FFT_N / 256, 256, 0, stream>>>(tw);
    kfft_kernel<<<H_DIM, NT, 0, stream>>>(k, tw, Kf);
    conv_kernel<<<(B_DIM / 2) * H_DIM, NT, 0, stream>>>(u, D, tw, Kf, out);
}

// Round 2
// 252.607 us; speedup vs baseline: 1.1918x; 1.1918x over previous
//
#include <hip/hip_runtime.h>
#include <math.h>

#define FFT_N 16384
#define NT 512
#define RPT 32                          // complex elements per thread
#define LDS_FLOATS (FFT_N + (FFT_N >> 5))   // 16896 floats = 66 KiB (padded)
#define IDX(i) ((i) + ((i) >> 5))
#define B_DIM 8
#define H_DIM 256

__device__ __forceinline__ float2 cmul(float2 a, float2 b) {
    return make_float2(a.x * b.x - a.y * b.y, a.x * b.y + a.y * b.x);
}
__device__ __forceinline__ float2 cadd(float2 a, float2 b) { return make_float2(a.x + b.x, a.y + b.y); }
__device__ __forceinline__ float2 csub(float2 a, float2 b) { return make_float2(a.x - b.x, a.y - b.y); }
__device__ __forceinline__ float2 mulnegi(float2 z) { return make_float2(z.y, -z.x); }   // -i*z
__device__ __forceinline__ float2 mulposi(float2 z) { return make_float2(-z.y, z.x); }   // +i*z

// ---- radix-4 butterflies (same algebra as the verified round-1 kernel) ----
// DIF forward: (a,b,c,d) = x[base], x[base+q], x[base+2q], x[base+3q]
__device__ __forceinline__ void bfly4(float2& a, float2& b, float2& c, float2& d, float2 w1) {
    float2 apc = cadd(a, c), amc = csub(a, c);
    float2 bpd = cadd(b, d), bmd = csub(b, d);
    float2 w2 = cmul(w1, w1), w3 = cmul(w2, w1);
    float2 nib = mulnegi(bmd);
    a = cadd(apc, bpd);
    b = cmul(csub(apc, bpd), w2);
    c = cmul(cadd(amc, nib), w1);
    d = cmul(csub(amc, nib), w3);
}
__device__ __forceinline__ void bfly4_nw(float2& a, float2& b, float2& c, float2& d) {
    float2 apc = cadd(a, c), amc = csub(a, c);
    float2 bpd = cadd(b, d), bmd = csub(b, d);
    float2 nib = mulnegi(bmd);
    a = cadd(apc, bpd);
    b = csub(apc, bpd);
    c = cadd(amc, nib);
    d = csub(amc, nib);
}
// DIT inverse (twiddle conj applied inside); same slot mapping as round-1 fft_inv
__device__ __forceinline__ void ibfly4(float2& a, float2& b, float2& c, float2& d, float2 w) {
    float2 w1 = make_float2(w.x, -w.y);
    float2 w2 = cmul(w1, w1);
    float2 bt = cmul(b, w2), dt = cmul(d, w2);
    float2 A = cadd(a, bt), Bb = csub(a, bt);
    float2 C = cadd(c, dt), Dd = csub(c, dt);
    float2 Cw = cmul(C, w1);
    float2 Dw = mulposi(cmul(Dd, w1));
    a = cadd(A, Cw);  c = csub(A, Cw);
    b = cadd(Bb, Dw); d = csub(Bb, Dw);
}
__device__ __forceinline__ void ibfly4_nw(float2& a, float2& b, float2& c, float2& d) {
    float2 A = cadd(a, b), Bb = csub(a, b);
    float2 C = cadd(c, d), Dd = csub(c, d);
    float2 Dw = mulposi(Dd);
    a = cadd(A, C);  c = csub(A, C);
    b = cadd(Bb, Dw); d = csub(Bb, Dw);
}

// ---- register phases: two radix-4 DIF stages on r[32] ----
// lp = local twiddle offset (t / t&31 / t&1); P = t_pos step per j0; ST = twiddle stride of first stage
template<int P, int ST>
__device__ __forceinline__ void fwd_phase(float2 r[RPT], int lp, const float2* __restrict__ tw) {
#pragma unroll
    for (int j0 = 0; j0 < 8; ++j0)
        bfly4(r[j0], r[j0 + 8], r[j0 + 16], r[j0 + 24], tw[(lp + P * j0) * ST]);
#pragma unroll
    for (int m = 0; m < 8; ++m) {
        const int g = (m >> 1) * 8 + (m & 1);
        bfly4(r[g], r[g + 2], r[g + 4], r[g + 6], tw[(lp + P * (g & 1)) * (ST * 4)]);
    }
}
template<int P, int ST>
__device__ __forceinline__ void inv_phase(float2 r[RPT], int lp, const float2* __restrict__ tw) {
#pragma unroll
    for (int m = 0; m < 8; ++m) {
        const int g = (m >> 1) * 8 + (m & 1);
        ibfly4(r[g], r[g + 2], r[g + 4], r[g + 6], tw[(lp + P * (g & 1)) * (ST * 4)]);
    }
#pragma unroll
    for (int j0 = 0; j0 < 8; ++j0)
        ibfly4(r[j0], r[j0 + 8], r[j0 + 16], r[j0 + 24], tw[(lp + P * j0) * ST]);
}
__device__ __forceinline__ void fwd_phaseD(float2 r[RPT]) {
#pragma unroll
    for (int j0 = 0; j0 < 8; ++j0)
        bfly4_nw(r[4 * j0], r[4 * j0 + 1], r[4 * j0 + 2], r[4 * j0 + 3]);
}
__device__ __forceinline__ void inv_phaseD(float2 r[RPT]) {
#pragma unroll
    for (int j0 = 0; j0 < 8; ++j0)
        ibfly4_nw(r[4 * j0], r[4 * j0 + 1], r[4 * j0 + 2], r[4 * j0 + 3]);
}

// ---- layout index maps (natural array index held by thread t, slot j) ----
#define nA(t, j) ((t) + NT * (j))
#define nB(t, j) ((((t) >> 5) << 10) + ((t) & 31) + 32 * (j))
#define nC(t, j) ((((t) >> 1) << 6) + ((t) & 1) + 2 * (j))
#define nD(t, j) (32 * (t) + (j))

// component-wise exchange through a single 66 KiB float LDS buffer
#define EXCHANGE(NFROM, NTO)                                                        \
    do {                                                                            \
        _Pragma("unroll") for (int j = 0; j < RPT; ++j) lds[IDX(NFROM(t, j))] = r[j].x; \
        __syncthreads();                                                            \
        _Pragma("unroll") for (int j = 0; j < RPT; ++j) r[j].x = lds[IDX(NTO(t, j))];   \
        __syncthreads();                                                            \
        _Pragma("unroll") for (int j = 0; j < RPT; ++j) lds[IDX(NFROM(t, j))] = r[j].y; \
        __syncthreads();                                                            \
        _Pragma("unroll") for (int j = 0; j < RPT; ++j) r[j].y = lds[IDX(NTO(t, j))];   \
        __syncthreads();                                                            \
    } while (0)

__global__ void twiddle_init(float2* __restrict__ tw) {
    int t = blockIdx.x * blockDim.x + threadIdx.x;
    if (t < FFT_N) {
        float ang = -2.0f * 3.14159265358979323846f * (float)t / (float)FFT_N;
        float sv, cv;
        sincosf(ang, &sv, &cv);
        tw[t] = make_float2(cv, sv);
    }
}

// Forward FFT of kernel row h -> Kf[h] in DIF storage (digit-reversed) order.
__global__ __launch_bounds__(NT) void kfft_kernel(const float* __restrict__ k,
                                                  const float2* __restrict__ tw,
                                                  float2* __restrict__ Kf) {
    __shared__ float lds[LDS_FLOATS];
    const int h = blockIdx.x;
    const int t = threadIdx.x;
    const float* krow = k + (size_t)h * FFT_N;
    float2 r[RPT];
#pragma unroll
    for (int j = 0; j < RPT; ++j) r[j] = make_float2(krow[nA(t, j)], 0.f);
    fwd_phase<NT, 1>(r, t, tw);
    EXCHANGE(nA, nB);
    fwd_phase<32, 16>(r, t & 31, tw);
    EXCHANGE(nB, nC);
    fwd_phase<2, 256>(r, t & 1, tw);
    EXCHANGE(nC, nD);
    fwd_phaseD(r);
    float2* out = Kf + (size_t)h * FFT_N;
#pragma unroll
    for (int j = 0; j < RPT; ++j) out[nD(t, j)] = r[j];
}

// Pair of batch rows (2p, h), (2p+1, h) packed as z = u0 + i*u1.
__global__ __launch_bounds__(NT) void conv_kernel(const float* __restrict__ u,
                                                  const float* __restrict__ D,
                                                  const float2* __restrict__ tw,
                                                  const float2* __restrict__ Kf,
                                                  float* __restrict__ out) {
    __shared__ float lds[LDS_FLOATS];
    const int h = blockIdx.x & (H_DIM - 1);
    const int p = blockIdx.x >> 8;
    const int t = threadIdx.x;
    const size_t row0 = ((size_t)(2 * p) * H_DIM + h) * FFT_N;
    const size_t row1 = row0 + (size_t)H_DIM * FFT_N;
    const float* u0 = u + row0;
    const float* u1 = u + row1;

    float2 r[RPT];
#pragma unroll
    for (int j = 0; j < RPT; ++j) {
        const int n = nA(t, j);
        r[j] = make_float2(u0[n], u1[n]);
    }

    // forward DIF: stages {0,1} {2,3} {4,5} {6}
    fwd_phase<NT, 1>(r, t, tw);
    EXCHANGE(nA, nB);
    fwd_phase<32, 16>(r, t & 31, tw);
    EXCHANGE(nB, nC);
    fwd_phase<2, 256>(r, t & 1, tw);
    EXCHANGE(nC, nD);
    fwd_phaseD(r);

    // pointwise multiply in digit-reversed order (matches kfft storage) + 1/N
    {
        const float2* kfrow = Kf + (size_t)h * FFT_N;
        const float invN = 1.0f / (float)FFT_N;
#pragma unroll
        for (int j = 0; j < RPT; ++j) {
            const float2 w = kfrow[nD(t, j)];
            const float2 z = r[j];
            r[j] = make_float2((z.x * w.x - z.y * w.y) * invN,
                               (z.x * w.y + z.y * w.x) * invN);
        }
    }

    // inverse DIT: stages {6} {5,4} {3,2} {1,0}
    inv_phaseD(r);
    EXCHANGE(nD, nC);
    inv_phase<2, 256>(r, t & 1, tw);
    EXCHANGE(nC, nB);
    inv_phase<32, 16>(r, t & 31, tw);
    EXCHANGE(nB, nA);
    inv_phase<NT, 1>(r, t, tw);

    // epilogue: y + diag(D)*u, tanh, store (natural order, coalesced)
    const float dh = D[h * (H_DIM + 1)];
    float* o0 = out + row0;
    float* o1 = out + row1;
#pragma unroll
    for (int j = 0; j < RPT; ++j) {
        const int n = nA(t, j);
        const float a = u0[n];
        const float b = u1[n];
        o0[n] = tanhf(r[j].x + dh * a);
        o1[n] = tanhf(r[j].y + dh * b);
    }
}

extern "C" void kernel_launch(void* const* d_in, const int* in_sizes, int n_in,
                              void* d_out, int out_size, void* d_ws, size_t ws_size,
                              hipStream_t stream) {
    const float* u = (const float*)d_in[0];   // (B,H,L) f32
    const float* k = (const float*)d_in[1];   // (H,L)   f32
    const float* D = (const float*)d_in[2];   // (H,H)   f32
    float* out = (float*)d_out;

    float2* tw = (float2*)d_ws;               // 16384 float2 = 128 KiB
    float2* Kf = tw + FFT_N;                  // 256*16384 float2 = 32 MiB

    twiddle_init<<<FFT_N / 256, 256, 0, stream>>>(tw);
    kfft_kernel<<<H_DIM, NT, 0, stream>>>(k, tw, Kf);
    conv_kernel<<<(B_DIM / 2) * H_DIM, NT, 0, stream>>>(u, D, tw, Kf, out);
}